// Round 9
// baseline (1206.543 us; speedup 1.0000x reference)
//
#include <hip/hip_runtime.h>
#include <hip/hip_bf16.h>
#include <hip/hip_fp16.h>

typedef unsigned short u16;
typedef unsigned int u32;

#define N_NODES 100000
#define N_EDGES 600000
#define FIN_D   256
#define HDIM    128
#define NCLS    47
#define NOUT_D  10000
#define NCHUNK  196          // ceil(N_NODES/512)
#define NP2     100352       // NCHUNK*512, padded node count

typedef short bf16x8 __attribute__((ext_vector_type(8)));
typedef float f32x4  __attribute__((ext_vector_type(4)));

__device__ __forceinline__ float bf2f(u16 u) {
    union { u32 i; float f; } v; v.i = ((u32)u) << 16; return v.f;
}
__device__ __forceinline__ u16 f2bf(float f) {
    __hip_bfloat16 h = __float2bfloat16(f);
    return *reinterpret_cast<u16*>(&h);
}
__device__ __forceinline__ float loadF(const void* p, size_t i, bool f32) {
    if (f32) return ((const float*)p)[i];
    return bf2f(((const u16*)p)[i]);
}
__device__ __forceinline__ float wave_sum(float v) {
    #pragma unroll
    for (int o = 32; o > 0; o >>= 1) v += __shfl_xor(v, o, 64);
    return v;
}
__device__ __forceinline__ float wave_max(float v) {
    #pragma unroll
    for (int o = 32; o > 0; o >>= 1) v = fmaxf(v, __shfl_xor(v, o, 64));
    return v;
}
__device__ __forceinline__ int wave_sum_i(int v) {
    #pragma unroll
    for (int o = 32; o > 0; o >>= 1) v += __shfl_xor(v, o, 64);
    return v;
}
__device__ __forceinline__ int block_excl_scan_256(int v, int* wsum) {
    int lane = threadIdx.x & 63, wv = threadIdx.x >> 6;
    int inc = v;
    #pragma unroll
    for (int off = 1; off < 64; off <<= 1) {
        int u = __shfl_up(inc, off, 64);
        if (lane >= off) inc += u;
    }
    if (lane == 63) wsum[wv] = inc;
    __syncthreads();
    if (threadIdx.x == 0) {
        int a = 0;
        #pragma unroll
        for (int w = 0; w < 4; ++w) { int t = wsum[w]; wsum[w] = a; a += t; }
    }
    __syncthreads();
    return inc - v + wsum[wv];
}

// ---------------- dtype detector ---------------------------------------
__global__ __launch_bounds__(256) void dtype_detect_kernel(
    const u16* __restrict__ x, int* __restrict__ flag)
{
    __shared__ int cnt;
    if (threadIdx.x == 0) cnt = 0;
    __syncthreads();
    int local = 0;
    for (int i = threadIdx.x; i < 65536; i += 256) {
        u32 e = (x[i] >> 7) & 0xFF;
        if (e >= 200) local++;
    }
    atomicAdd(&cnt, local);
    __syncthreads();
    if (threadIdx.x == 0) *flag = (cnt > 16) ? 1 : 0;
}

// ---------------- CSR build (both edge lists per dispatch) --------------
__global__ __launch_bounds__(256) void hist2_kernel(
    const int* __restrict__ dst, int* __restrict__ deg2, int egrid)
{
    int half = (blockIdx.x >= egrid) ? 1 : 0;
    int e = (blockIdx.x - half * egrid) * 256 + threadIdx.x;
    if (e < N_EDGES) atomicAdd(&deg2[half * NP2 + dst[half * N_EDGES + e]], 1);
}

__global__ __launch_bounds__(256) void csum2_kernel(
    const int* __restrict__ deg2, int* __restrict__ csum)
{
    __shared__ int ws[4];
    int half = (blockIdx.x >= NCHUNK) ? 1 : 0;
    int b = blockIdx.x - half * NCHUNK;
    int i0 = half * NP2 + b * 512 + threadIdx.x;
    int v = 0;
    if (b * 512 + threadIdx.x < N_NODES) v += deg2[i0];
    if (b * 512 + threadIdx.x + 256 < N_NODES) v += deg2[i0 + 256];
    v = wave_sum_i(v);
    int lane = threadIdx.x & 63, wv = threadIdx.x >> 6;
    if (lane == 0) ws[wv] = v;
    __syncthreads();
    if (threadIdx.x == 0)
        csum[blockIdx.x] = ws[0] + ws[1] + ws[2] + ws[3];
}

// exclusive-scan the per-bucket counts; write both coff (read-only use)
// and bcur (pass-1 append cursors).
__global__ __launch_bounds__(256) void coff2_kernel(
    const int* __restrict__ csum, int* __restrict__ coff,
    int* __restrict__ bcur)
{
    __shared__ int wsum[4];
    int t = threadIdx.x;
    for (int h = 0; h < 2; ++h) {
        int v = (t < NCHUNK) ? csum[h * NCHUNK + t] : 0;
        int excl = block_excl_scan_256(v, wsum);
        if (t < NCHUNK) {
            coff[h * NCHUNK + t] = excl;
            bcur[h * NCHUNK + t] = excl;
        }
        __syncthreads();
    }
}

__global__ __launch_bounds__(256) void scan2_kernel(
    const int* __restrict__ deg2, const int* __restrict__ coff,
    int* __restrict__ rp0, int* __restrict__ rp1)
{
    __shared__ int wsum[4];
    int half = (blockIdx.x >= NCHUNK) ? 1 : 0;
    int b = blockIdx.x - half * NCHUNK;
    const int* deg = deg2 + half * NP2;
    int* rp = half ? rp1 : rp0;
    int t = threadIdx.x;
    int i0 = b * 512 + 2 * t;
    int d0 = (i0 < N_NODES) ? deg[i0] : 0;
    int d1 = (i0 + 1 < N_NODES) ? deg[i0 + 1] : 0;
    int excl = block_excl_scan_256(d0 + d1, wsum);
    int base = coff[half * NCHUNK + b] + excl;
    if (i0 < N_NODES)     rp[i0] = base;
    if (i0 + 1 < N_NODES) rp[i0 + 1] = base + d0;
    if (b == 0 && t == 0) rp[N_NODES] = N_EDGES;
}

// Pass 1: append (src', dst) pairs into per-bucket streams (bucket = dst>>9).
// Appends fill cachelines sequentially -> low write amplification.
__global__ __launch_bounds__(256) void bucket_scatter_kernel(
    const int* __restrict__ src, const int* __restrict__ dst,
    const int* __restrict__ comp1,
    int* __restrict__ bcur, int2* __restrict__ tmp, int egrid)
{
    int half = (blockIdx.x >= egrid) ? 1 : 0;
    int e = (blockIdx.x - half * egrid) * 256 + threadIdx.x;
    if (e >= N_EDGES) return;
    int ge = half * N_EDGES + e;
    int d = dst[ge];
    int s = src[ge];
    if (half) s = comp1[s];
    int pos = atomicAdd(&bcur[half * NCHUNK + (d >> 9)], 1);
    tmp[(size_t)half * N_EDGES + pos] = make_int2(s, d);
}

// Pass 2: one block per bucket; LDS cursors from rp; sequential read of the
// bucket's pairs, LDS-atomic rank, write into the bucket's contiguous
// output window of ei (L2-resident, written once).
__global__ __launch_bounds__(256) void bucket_sort_kernel(
    const int2* __restrict__ tmp,
    const int* __restrict__ rp0, const int* __restrict__ rp1,
    const int* __restrict__ coff, const int* __restrict__ csum,
    int* __restrict__ ei0, int* __restrict__ ei1)
{
    __shared__ int cur[512];
    int half = (blockIdx.x >= NCHUNK) ? 1 : 0;
    int b = blockIdx.x - half * NCHUNK;
    const int* rp = half ? rp1 : rp0;
    int* ei = half ? ei1 : ei0;
    int n0 = b * 512;
    #pragma unroll
    for (int i = threadIdx.x; i < 512; i += 256) {
        int n = n0 + i;
        cur[i] = (n < N_NODES) ? rp[n] : 0;
    }
    __syncthreads();
    int beg = coff[half * NCHUNK + b];
    int end = beg + csum[half * NCHUNK + b];
    for (int i = beg + threadIdx.x; i < end; i += 256) {
        int2 p = tmp[(size_t)half * N_EDGES + i];
        int pos = atomicAdd(&cur[p.y & 511], 1);
        ei[pos] = p.x;
    }
}

// ---------------- Weight pre-pack into MFMA B-fragment order -----------
// Packed element o = ((kidx*8 + ct)*64 + lane)*8 + j maps to
// B[k = kidx*32 + (lane>>4)*8 + j][n = ct*16 + (lane&15)].
// enc (K=256) at [0, 32768); gcn layer l (K=128) at 32768 + l*16384.
__global__ __launch_bounds__(256) void pack_b_kernel(
    const void* __restrict__ enc_w, const void* __restrict__ gcn_w,
    const int* __restrict__ dt, u16* __restrict__ Bp)
{
    const bool f32 = (*dt != 0);
    int o = blockIdx.x * 256 + threadIdx.x;
    if (o >= 32768 + 3 * 16384) return;
    const void* srcp; size_t soff; int m;
    if (o < 32768) { srcp = enc_w; soff = 0; m = o; }
    else {
        int l = (o - 32768) >> 14;
        srcp = gcn_w; soff = (size_t)l * 16384; m = (o - 32768) & 16383;
    }
    int j    = m & 7;
    int lane = (m >> 3) & 63;
    int ct   = (m >> 9) & 7;
    int kidx = m >> 12;
    int k = kidx * 32 + (lane >> 4) * 8 + j;
    int n = ct * 16 + (lane & 15);
    Bp[o] = f2bf(loadF(srcp, soff + (size_t)k * HDIM + n, f32));
}

// ---------------- Encoder GEMM: HB0 = bf16(x @ enc_w + enc_b) ----------
// Barrier-free, zero-LDS: A and B fragments loaded directly from global
// in MFMA layout. 64-row tile per 256-thread block.
__global__ __launch_bounds__(256) void enc_gemm_kernel(
    const void* __restrict__ Araw, const u16* __restrict__ Bp,
    const void* __restrict__ bias, const int* __restrict__ dt,
    u16* __restrict__ OutBF)
{
    const bool f32 = (*dt != 0);
    const int tid  = threadIdx.x;
    const int w    = tid >> 6;
    const int lane = tid & 63;
    const int quad = lane >> 4;
    const int cl   = lane & 15;
    const int m0   = blockIdx.x * 64;
    int arow = m0 + w * 16 + cl;
    if (arow >= N_NODES) arow = N_NODES - 1;   // clamp; stores guarded below

    f32x4 acc[8];
    #pragma unroll
    for (int ct = 0; ct < 8; ++ct) acc[ct] = (f32x4){0.f, 0.f, 0.f, 0.f};

    #pragma unroll
    for (int kidx = 0; kidx < 8; ++kidx) {
        bf16x8 a;
        if (!f32) {
            a = *(const bf16x8*)((const u16*)Araw +
                 (size_t)arow * FIN_D + kidx * 32 + quad * 8);
        } else {
            const float* ap = (const float*)Araw +
                 (size_t)arow * FIN_D + kidx * 32 + quad * 8;
            float4 v0 = *(const float4*)ap;
            float4 v1 = *(const float4*)(ap + 4);
            u32 p0 = (u32)f2bf(v0.x) | ((u32)f2bf(v0.y) << 16);
            u32 p1 = (u32)f2bf(v0.z) | ((u32)f2bf(v0.w) << 16);
            u32 p2 = (u32)f2bf(v1.x) | ((u32)f2bf(v1.y) << 16);
            u32 p3 = (u32)f2bf(v1.z) | ((u32)f2bf(v1.w) << 16);
            union { u32 u[4]; bf16x8 v; } cv;
            cv.u[0] = p0; cv.u[1] = p1; cv.u[2] = p2; cv.u[3] = p3;
            a = cv.v;
        }
        const u16* bb = Bp + ((size_t)(kidx * 8) * 64 + lane) * 8;
        #pragma unroll
        for (int ct = 0; ct < 8; ++ct) {
            bf16x8 b = *(const bf16x8*)(bb + (size_t)ct * 512);
            acc[ct] = __builtin_amdgcn_mfma_f32_16x16x32_bf16(a, b, acc[ct], 0, 0, 0);
        }
    }

    #pragma unroll
    for (int reg = 0; reg < 4; ++reg) {
        int grow = m0 + w * 16 + quad * 4 + reg;
        if (grow >= N_NODES) continue;
        #pragma unroll
        for (int ct = 0; ct < 8; ++ct) {
            int col = ct * 16 + cl;
            float v = acc[ct][reg] + loadF(bias, col, f32);
            OutBF[(size_t)grow * HDIM + col] = f2bf(v);
        }
    }
}

// ---------------- Softmax aggregation -> bf16 A-matrix -----------------
// Wave per dst node; edges processed in batches of 8 (independent eidx
// fetches, then independent row gathers) to break the latency chain.
template<bool OWN_MAP>
__global__ __launch_bounds__(256) void agg_msg_kernel(
    const int* __restrict__ rp, const int* __restrict__ eidx,
    const u16* __restrict__ HBin, const int* __restrict__ own_map,
    u16* __restrict__ Amsg)
{
    int wave = threadIdx.x >> 6;
    int lane = threadIdx.x & 63;
    int n = blockIdx.x * 4 + wave;
    if (n >= N_NODES) return;
    const u32* HB32 = (const u32*)HBin;
    int nn = OWN_MAP ? own_map[n] : n;
    u32 own = HB32[(size_t)nn * 64 + lane];
    int beg = rp[n], end = rp[n + 1];
    float den0 = 0.f, den1 = 0.f, num0 = 0.f, num1 = 0.f;
    for (int j0 = beg; j0 < end; j0 += 8) {
        int cnt = end - j0; if (cnt > 8) cnt = 8;
        int ss[8];
        #pragma unroll
        for (int t = 0; t < 8; ++t) {
            int j = j0 + t;
            ss[t] = eidx[j < end ? j : end - 1];
        }
        u32 hh[8];
        #pragma unroll
        for (int t = 0; t < 8; ++t)
            hh[t] = HB32[(size_t)ss[t] * 64 + lane];
        #pragma unroll
        for (int t = 0; t < 8; ++t) {
            float valid = (t < cnt) ? 1.f : 0.f;
            float m0 = fmaxf(bf2f((u16)(hh[t] & 0xffff)), 0.f) + 1e-7f;
            float m1 = fmaxf(bf2f((u16)(hh[t] >> 16)),    0.f) + 1e-7f;
            float e0 = __expf(m0) * valid, e1 = __expf(m1) * valid;
            den0 += e0; num0 += m0 * e0;
            den1 += e1; num1 += m1 * e1;
        }
    }
    float a0 = num0 / (den0 + 1e-16f) + bf2f((u16)(own & 0xffff));
    float a1 = num1 / (den1 + 1e-16f) + bf2f((u16)(own >> 16));
    ((u32*)Amsg)[(size_t)n * 64 + lane] = (u32)f2bf(a0) | ((u32)f2bf(a1) << 16);
}

// ---------------- Conv GEMM: h = Amsg @ Wl + bias (+fp16 res) ----------
// B (32 KB) staged to LDS once (single barrier); A fragments direct from
// global; barrier-free K-loop. 64-row tile per block.
template<bool RES, bool OWN_MAP, bool WRITE_LN>
__global__ __launch_bounds__(256) void conv_gemm_kernel(
    const u16* __restrict__ Amsg, const int* __restrict__ own_map,
    const u16* __restrict__ Bp, int Bpbase,
    const void* __restrict__ bias, int biasoff,
    const __half* __restrict__ Resid,
    const void* __restrict__ lng, const void* __restrict__ lnb, int lnoff,
    const int* __restrict__ dt,
    __half* __restrict__ OutH, u16* __restrict__ HBout)
{
    const bool f32 = (*dt != 0);
    __shared__ u16 Bsh[16384];         // full 128x128 bf16 W, fragment order
    const int tid  = threadIdx.x;
    const int w    = tid >> 6;
    const int lane = tid & 63;
    const int quad = lane >> 4;
    const int cl   = lane & 15;
    const int m0   = blockIdx.x * 64;

    {
        const uint4* bsrc = (const uint4*)(Bp + Bpbase);
        uint4* bdst = (uint4*)Bsh;
        #pragma unroll
        for (int j = 0; j < 8; ++j)
            bdst[j * 256 + tid] = bsrc[j * 256 + tid];
    }

    int arow = m0 + w * 16 + cl;
    if (arow >= N_NODES) arow = N_NODES - 1;
    bf16x8 afr[4];
    #pragma unroll
    for (int kidx = 0; kidx < 4; ++kidx)
        afr[kidx] = *(const bf16x8*)(Amsg + (size_t)arow * HDIM + kidx * 32 + quad * 8);

    __syncthreads();

    f32x4 acc[8];
    #pragma unroll
    for (int ct = 0; ct < 8; ++ct) acc[ct] = (f32x4){0.f, 0.f, 0.f, 0.f};
    #pragma unroll
    for (int kidx = 0; kidx < 4; ++kidx) {
        const u16* bb = Bsh + ((size_t)(kidx * 8) * 64 + lane) * 8;
        #pragma unroll
        for (int ct = 0; ct < 8; ++ct) {
            bf16x8 b = *(const bf16x8*)(bb + (size_t)ct * 512);
            acc[ct] = __builtin_amdgcn_mfma_f32_16x16x32_bf16(afr[kidx], b, acc[ct], 0, 0, 0);
        }
    }

    // ---- epilogue: +bias (+fp16 residual) -> fp16 h; optional LN+ReLU ----
    #pragma unroll
    for (int reg = 0; reg < 4; ++reg) {
        int n = m0 + w * 16 + quad * 4 + reg;
        if (n >= N_NODES) continue;            // uniform across 16-lane group
        size_t rrow = 0;
        if (RES) rrow = (size_t)(OWN_MAP ? own_map[n] : n) * HDIM;
        float v[8];
        float s1 = 0.f, s2 = 0.f;
        #pragma unroll
        for (int ct = 0; ct < 8; ++ct) {
            int col = ct * 16 + cl;
            float x = acc[ct][reg] + loadF(bias, biasoff + col, f32);
            if (RES) x += __half2float(Resid[rrow + col]);
            v[ct] = x;
            OutH[(size_t)n * HDIM + col] = __float2half(x);
            s1 += x; s2 += x * x;
        }
        if (WRITE_LN) {
            #pragma unroll
            for (int o = 1; o < 16; o <<= 1) {
                s1 += __shfl_xor(s1, o, 64);
                s2 += __shfl_xor(s2, o, 64);
            }
            float mu = s1 * (1.0f / 128.0f);
            float var = s2 * (1.0f / 128.0f) - mu * mu;
            float rs = rsqrtf(fmaxf(var, 0.f) + 1e-5f);
            #pragma unroll
            for (int ct = 0; ct < 8; ++ct) {
                int col = ct * 16 + cl;
                float y = fmaxf((v[ct] - mu) * rs * loadF(lng, lnoff + col, f32)
                                + loadF(lnb, lnoff + col, f32), 0.f);
                HBout[(size_t)n * HDIM + col] = f2bf(y);
            }
        }
    }
}

// ---------------- Final: gather -> LN -> ReLU -> pred -> log_softmax ---
__global__ __launch_bounds__(64) void final_head_kernel(
    const __half* __restrict__ Hsrc, const int* __restrict__ map1,
    const int* __restrict__ fmap,
    const void* __restrict__ g, const void* __restrict__ b, int goff,
    const void* __restrict__ pw, const void* __restrict__ pb,
    const int* __restrict__ dt, void* __restrict__ out)
{
    const bool f32 = (*dt != 0);
    __shared__ float sh[HDIM];
    int i = blockIdx.x;
    int lane = threadIdx.x;
    int jj = map1[fmap[i]];
    __half2 hv = *((const __half2*)(Hsrc + (size_t)jj * HDIM) + lane);
    float2 v = __half22float2(hv);
    float mu = wave_sum(v.x + v.y) * (1.0f / 128.0f);
    float d0 = v.x - mu, d1 = v.y - mu;
    float var = wave_sum(d0 * d0 + d1 * d1) * (1.0f / 128.0f);
    float rs = rsqrtf(var + 1e-5f);
    int f0 = lane * 2;
    sh[f0]     = fmaxf(d0 * rs * loadF(g, goff + f0, f32)     + loadF(b, goff + f0, f32),     0.0f);
    sh[f0 + 1] = fmaxf(d1 * rs * loadF(g, goff + f0 + 1, f32) + loadF(b, goff + f0 + 1, f32), 0.0f);
    __syncthreads();
    float acc = -1e30f;
    if (lane < NCLS) {
        acc = loadF(pb, lane, f32);
        #pragma unroll 4
        for (int k = 0; k < HDIM; ++k)
            acc = fmaf(sh[k], loadF(pw, k * NCLS + lane, f32), acc);
    }
    float mx = wave_max(acc);
    float ex = (lane < NCLS) ? __expf(acc - mx) : 0.0f;
    float sum = wave_sum(ex);
    if (lane < NCLS) {
        float r = acc - mx - logf(sum);
        if (f32) ((float*)out)[(size_t)i * NCLS + lane] = r;
        else     ((u16*)out)[(size_t)i * NCLS + lane] = f2bf(r);
    }
}

extern "C" void kernel_launch(void* const* d_in, const int* in_sizes, int n_in,
                              void* d_out, int out_size, void* d_ws, size_t ws_size,
                              hipStream_t stream) {
    const void* x       = d_in[0];
    const int* src      = (const int*)d_in[1];
    const int* dst      = (const int*)d_in[2];
    const int* node_map = (const int*)d_in[3];
    const int* fmap     = (const int*)d_in[4];
    const void* enc_w   = d_in[5];
    const void* enc_b   = d_in[6];
    const void* gcn_w   = d_in[7];
    const void* gcn_b   = d_in[8];
    const void* ln_g    = d_in[9];
    const void* ln_b    = d_in[10];
    const void* pred_w  = d_in[11];
    const void* pred_b  = d_in[12];

    char* ws = (char*)d_ws;
    const size_t szH = (size_t)N_NODES * HDIM * sizeof(u16);     // 25.6 MB
    __half* Pa  = (__half*)ws;  ws += szH;   // h1, then h3 (fp16)
    __half* Pb  = (__half*)ws;  ws += szH;   // h2 (fp16)
    u16*   HBa  = (u16*)ws;     ws += szH;   // msg0, then msg2 (bf16)
    u16*   HBb  = (u16*)ws;     ws += szH;   // msg1 (bf16)
    u16*   Amsg = (u16*)ws;     ws += szH;   // per-layer GEMM A matrix (bf16)
    int*   FLAG = (int*)ws;     ws += 1024;
    u16*   Bp   = (u16*)ws;     ws += (size_t)(32768 + 3 * 16384) * 2 + 1024;
    int*  deg2  = (int*)ws;  ws += (size_t)2 * NP2 * 4;
    int*  rp0   = (int*)ws;  ws += (size_t)(N_NODES + 2) * 4;
    int*  rp1   = (int*)ws;  ws += (size_t)(N_NODES + 2) * 4;
    int*  ei0   = (int*)ws;  ws += (size_t)N_EDGES * 4;
    int*  ei1   = (int*)ws;  ws += (size_t)N_EDGES * 4;
    int2* tmp   = (int2*)ws; ws += (size_t)2 * N_EDGES * 8;
    int*  csum  = (int*)ws;  ws += 2048;
    int*  coff  = (int*)ws;  ws += 2048;
    int*  bcur  = (int*)ws;  ws += 2048;

    dim3 blk(256);
    const int ggrid = (N_NODES + 63) / 64;       // 1563
    const int egrid = (N_EDGES + 255) / 256;
    const int agrid = (N_NODES + 3) / 4;
    const int pgrid = (32768 + 3 * 16384 + 255) / 256;

    dtype_detect_kernel<<<1, blk, 0, stream>>>((const u16*)x, FLAG);
    pack_b_kernel<<<pgrid, blk, 0, stream>>>(enc_w, gcn_w, FLAG, Bp);

    // ---- CSR build, both edge lists, bucketed two-pass scatter ----
    hipMemsetAsync(deg2, 0, (size_t)2 * NP2 * 4, stream);
    hist2_kernel<<<2 * egrid, blk, 0, stream>>>(dst, deg2, egrid);
    csum2_kernel<<<2 * NCHUNK, blk, 0, stream>>>(deg2, csum);
    coff2_kernel<<<1, blk, 0, stream>>>(csum, coff, bcur);
    scan2_kernel<<<2 * NCHUNK, blk, 0, stream>>>(deg2, coff, rp0, rp1);
    bucket_scatter_kernel<<<2 * egrid, blk, 0, stream>>>(src, dst, node_map,
                                                         bcur, tmp, egrid);
    bucket_sort_kernel<<<2 * NCHUNK, blk, 0, stream>>>(tmp, rp0, rp1, coff, csum,
                                                       ei0, ei1);

    // encoder: HBa = bf16(x @ enc_w + enc_b)   (= msg matrix for conv0)
    enc_gemm_kernel<<<ggrid, blk, 0, stream>>>(x, Bp, enc_b, FLAG, HBa);

    // layer 0: Amsg = agg0(HBa)+HBa ; Pa = Amsg@w0+b0 ; HBb = relu(LN(Pa,ln0))
    agg_msg_kernel<false><<<agrid, blk, 0, stream>>>(rp0, ei0, HBa, nullptr, Amsg);
    conv_gemm_kernel<false, false, true><<<ggrid, blk, 0, stream>>>(
        Amsg, nullptr, Bp, 32768, gcn_b, 0, nullptr,
        ln_g, ln_b, 0, FLAG, Pa, HBb);

    // layer 1: Amsg = agg0(HBb)+HBb ; Pb = Amsg@w1+b1+Pa ; HBa = relu(LN(Pb,ln1))
    agg_msg_kernel<false><<<agrid, blk, 0, stream>>>(rp0, ei0, HBb, nullptr, Amsg);
    conv_gemm_kernel<true, false, true><<<ggrid, blk, 0, stream>>>(
        Amsg, nullptr, Bp, 32768 + 16384, gcn_b, 128, Pa,
        ln_g, ln_b, 128, FLAG, Pb, HBa);

    // layer 2 (permute via node_map[0], index-composed into CSR1):
    // Amsg = agg1(HBa)+HBa[map0] ; Pa = Amsg@w2+b2+Pb[map0]
    agg_msg_kernel<true><<<agrid, blk, 0, stream>>>(rp1, ei1, HBa, node_map, Amsg);
    conv_gemm_kernel<true, true, false><<<ggrid, blk, 0, stream>>>(
        Amsg, node_map, Bp, 32768 + 2 * 16384, gcn_b, 256, Pb,
        ln_g, ln_b, 256, FLAG, Pa, nullptr);

    // final head: Pa[node_map[1][final_map[i]]] -> LN(ln2) -> pred -> log_softmax
    final_head_kernel<<<NOUT_D, dim3(64), 0, stream>>>(
        Pa, node_map + N_NODES, fmap, ln_g, ln_b, 256, pred_w, pred_b, FLAG,
        (void*)d_out);
}

// Round 10
// 631.990 us; speedup vs baseline: 1.9091x; 1.9091x over previous
//
#include <hip/hip_runtime.h>
#include <hip/hip_bf16.h>
#include <hip/hip_fp16.h>

typedef unsigned short u16;
typedef unsigned int u32;

#define N_NODES 100000
#define N_EDGES 600000
#define FIN_D   256
#define HDIM    128
#define NCLS    47
#define NOUT_D  10000
#define NCHUNK  196          // ceil(N_NODES/512)
#define NP2     100352       // NCHUNK*512, padded node count
#define PCH     4096         // edges per partition block
#define PNB     ((N_EDGES + PCH - 1) / PCH)   // 147

typedef short bf16x8 __attribute__((ext_vector_type(8)));
typedef float f32x4  __attribute__((ext_vector_type(4)));

__device__ __forceinline__ float bf2f(u16 u) {
    union { u32 i; float f; } v; v.i = ((u32)u) << 16; return v.f;
}
__device__ __forceinline__ u16 f2bf(float f) {
    __hip_bfloat16 h = __float2bfloat16(f);
    return *reinterpret_cast<u16*>(&h);
}
__device__ __forceinline__ float loadF(const void* p, size_t i, bool f32) {
    if (f32) return ((const float*)p)[i];
    return bf2f(((const u16*)p)[i]);
}
__device__ __forceinline__ float wave_sum(float v) {
    #pragma unroll
    for (int o = 32; o > 0; o >>= 1) v += __shfl_xor(v, o, 64);
    return v;
}
__device__ __forceinline__ float wave_max(float v) {
    #pragma unroll
    for (int o = 32; o > 0; o >>= 1) v = fmaxf(v, __shfl_xor(v, o, 64));
    return v;
}
__device__ __forceinline__ int wave_sum_i(int v) {
    #pragma unroll
    for (int o = 32; o > 0; o >>= 1) v += __shfl_xor(v, o, 64);
    return v;
}
__device__ __forceinline__ int block_excl_scan_256(int v, int* wsum) {
    int lane = threadIdx.x & 63, wv = threadIdx.x >> 6;
    int inc = v;
    #pragma unroll
    for (int off = 1; off < 64; off <<= 1) {
        int u = __shfl_up(inc, off, 64);
        if (lane >= off) inc += u;
    }
    if (lane == 63) wsum[wv] = inc;
    __syncthreads();
    if (threadIdx.x == 0) {
        int a = 0;
        #pragma unroll
        for (int w = 0; w < 4; ++w) { int t = wsum[w]; wsum[w] = a; a += t; }
    }
    __syncthreads();
    return inc - v + wsum[wv];
}

// ---------------- dtype detector ---------------------------------------
__global__ __launch_bounds__(256) void dtype_detect_kernel(
    const u16* __restrict__ x, int* __restrict__ flag)
{
    __shared__ int cnt;
    if (threadIdx.x == 0) cnt = 0;
    __syncthreads();
    int local = 0;
    for (int i = threadIdx.x; i < 65536; i += 256) {
        u32 e = (x[i] >> 7) & 0xFF;
        if (e >= 200) local++;
    }
    atomicAdd(&cnt, local);
    __syncthreads();
    if (threadIdx.x == 0) *flag = (cnt > 16) ? 1 : 0;
}

// ---------------- CSR build (both edge lists per dispatch) --------------
__global__ __launch_bounds__(256) void hist2_kernel(
    const int* __restrict__ dst, int* __restrict__ deg2, int egrid)
{
    int half = (blockIdx.x >= egrid) ? 1 : 0;
    int e = (blockIdx.x - half * egrid) * 256 + threadIdx.x;
    if (e < N_EDGES) atomicAdd(&deg2[half * NP2 + dst[half * N_EDGES + e]], 1);
}

__global__ __launch_bounds__(256) void csum2_kernel(
    const int* __restrict__ deg2, int* __restrict__ csum)
{
    __shared__ int ws[4];
    int half = (blockIdx.x >= NCHUNK) ? 1 : 0;
    int b = blockIdx.x - half * NCHUNK;
    int i0 = half * NP2 + b * 512 + threadIdx.x;
    int v = 0;
    if (b * 512 + threadIdx.x < N_NODES) v += deg2[i0];
    if (b * 512 + threadIdx.x + 256 < N_NODES) v += deg2[i0 + 256];
    v = wave_sum_i(v);
    int lane = threadIdx.x & 63, wv = threadIdx.x >> 6;
    if (lane == 0) ws[wv] = v;
    __syncthreads();
    if (threadIdx.x == 0)
        csum[blockIdx.x] = ws[0] + ws[1] + ws[2] + ws[3];
}

// exclusive-scan per-bucket counts; coff compact, bcur padded 1/cacheline.
__global__ __launch_bounds__(256) void coff2_kernel(
    const int* __restrict__ csum, int* __restrict__ coff,
    int* __restrict__ bcur)
{
    __shared__ int wsum[4];
    int t = threadIdx.x;
    for (int h = 0; h < 2; ++h) {
        int v = (t < NCHUNK) ? csum[h * NCHUNK + t] : 0;
        int excl = block_excl_scan_256(v, wsum);
        if (t < NCHUNK) {
            coff[h * NCHUNK + t] = excl;
            bcur[(h * NCHUNK + t) * 16] = excl;   // 64B-padded cursor
        }
        __syncthreads();
    }
}

__global__ __launch_bounds__(256) void scan2_kernel(
    const int* __restrict__ deg2, const int* __restrict__ coff,
    int* __restrict__ rp0, int* __restrict__ rp1)
{
    __shared__ int wsum[4];
    int half = (blockIdx.x >= NCHUNK) ? 1 : 0;
    int b = blockIdx.x - half * NCHUNK;
    const int* deg = deg2 + half * NP2;
    int* rp = half ? rp1 : rp0;
    int t = threadIdx.x;
    int i0 = b * 512 + 2 * t;
    int d0 = (i0 < N_NODES) ? deg[i0] : 0;
    int d1 = (i0 + 1 < N_NODES) ? deg[i0 + 1] : 0;
    int excl = block_excl_scan_256(d0 + d1, wsum);
    int base = coff[half * NCHUNK + b] + excl;
    if (i0 < N_NODES)     rp[i0] = base;
    if (i0 + 1 < N_NODES) rp[i0 + 1] = base + d0;
    if (b == 0 && t == 0) rp[N_NODES] = N_EDGES;
}

// Pass 1: block-local radix partition. Each block takes 4096 edges, LDS
// histogram by bucket (dst>>9), ONE global atomic per (block,bucket) onto
// a cacheline-padded cursor, then contiguous per-bucket writes to tmp.
__global__ __launch_bounds__(256) void bucket_part_kernel(
    const int* __restrict__ src, const int* __restrict__ dst,
    const int* __restrict__ comp1,
    int* __restrict__ bcur, int2* __restrict__ tmp)
{
    __shared__ int hist[NCHUNK];
    __shared__ int base[NCHUNK];
    int half = (blockIdx.x >= PNB) ? 1 : 0;
    int b = blockIdx.x - half * PNB;
    int e0 = b * PCH;
    for (int i = threadIdx.x; i < NCHUNK; i += 256) hist[i] = 0;
    __syncthreads();

    int2 loc[16];
    #pragma unroll
    for (int t = 0; t < 16; ++t) {
        int e = e0 + t * 256 + threadIdx.x;
        loc[t].y = -1;
        if (e < N_EDGES) {
            int ge = half * N_EDGES + e;
            int d = dst[ge];
            int s = src[ge];
            if (half) s = comp1[s];
            loc[t] = make_int2(s, d);
            atomicAdd(&hist[d >> 9], 1);
        }
    }
    __syncthreads();
    for (int i = threadIdx.x; i < NCHUNK; i += 256) {
        int h = hist[i];
        base[i] = (h > 0) ? atomicAdd(&bcur[(half * NCHUNK + i) * 16], h) : 0;
        hist[i] = 0;      // reuse as block-local cursor
    }
    __syncthreads();
    #pragma unroll
    for (int t = 0; t < 16; ++t) {
        if (loc[t].y >= 0) {
            int bk = loc[t].y >> 9;
            int pos = base[bk] + atomicAdd(&hist[bk], 1);
            tmp[(size_t)half * N_EDGES + pos] = loc[t];
        }
    }
}

// Pass 2: one block per bucket; LDS cursors from rp; sequential read of the
// bucket's pairs, LDS-atomic rank, write into the bucket's contiguous
// output window of ei (L2-resident, written once).
__global__ __launch_bounds__(256) void bucket_sort_kernel(
    const int2* __restrict__ tmp,
    const int* __restrict__ rp0, const int* __restrict__ rp1,
    const int* __restrict__ coff, const int* __restrict__ csum,
    int* __restrict__ ei0, int* __restrict__ ei1)
{
    __shared__ int cur[512];
    int half = (blockIdx.x >= NCHUNK) ? 1 : 0;
    int b = blockIdx.x - half * NCHUNK;
    const int* rp = half ? rp1 : rp0;
    int* ei = half ? ei1 : ei0;
    int n0 = b * 512;
    #pragma unroll
    for (int i = threadIdx.x; i < 512; i += 256) {
        int n = n0 + i;
        cur[i] = (n < N_NODES) ? rp[n] : 0;
    }
    __syncthreads();
    int beg = coff[half * NCHUNK + b];
    int end = beg + csum[half * NCHUNK + b];
    for (int i = beg + threadIdx.x; i < end; i += 256) {
        int2 p = tmp[(size_t)half * N_EDGES + i];
        int pos = atomicAdd(&cur[p.y & 511], 1);
        ei[pos] = p.x;
    }
}

// ---------------- Weight pre-pack into MFMA B-fragment order -----------
__global__ __launch_bounds__(256) void pack_b_kernel(
    const void* __restrict__ enc_w, const void* __restrict__ gcn_w,
    const int* __restrict__ dt, u16* __restrict__ Bp)
{
    const bool f32 = (*dt != 0);
    int o = blockIdx.x * 256 + threadIdx.x;
    if (o >= 32768 + 3 * 16384) return;
    const void* srcp; size_t soff; int m;
    if (o < 32768) { srcp = enc_w; soff = 0; m = o; }
    else {
        int l = (o - 32768) >> 14;
        srcp = gcn_w; soff = (size_t)l * 16384; m = (o - 32768) & 16383;
    }
    int j    = m & 7;
    int lane = (m >> 3) & 63;
    int ct   = (m >> 9) & 7;
    int kidx = m >> 12;
    int k = kidx * 32 + (lane >> 4) * 8 + j;
    int n = ct * 16 + (lane & 15);
    Bp[o] = f2bf(loadF(srcp, soff + (size_t)k * HDIM + n, f32));
}

// ---------------- Encoder GEMM: HB0 = bf16(x @ enc_w + enc_b) ----------
// Barrier-free, zero-LDS: A and B fragments direct from global.
__global__ __launch_bounds__(256) void enc_gemm_kernel(
    const void* __restrict__ Araw, const u16* __restrict__ Bp,
    const void* __restrict__ bias, const int* __restrict__ dt,
    u16* __restrict__ OutBF)
{
    const bool f32 = (*dt != 0);
    const int tid  = threadIdx.x;
    const int w    = tid >> 6;
    const int lane = tid & 63;
    const int quad = lane >> 4;
    const int cl   = lane & 15;
    const int m0   = blockIdx.x * 64;
    int arow = m0 + w * 16 + cl;
    if (arow >= N_NODES) arow = N_NODES - 1;

    f32x4 acc[8];
    #pragma unroll
    for (int ct = 0; ct < 8; ++ct) acc[ct] = (f32x4){0.f, 0.f, 0.f, 0.f};

    #pragma unroll
    for (int kidx = 0; kidx < 8; ++kidx) {
        bf16x8 a;
        if (!f32) {
            a = *(const bf16x8*)((const u16*)Araw +
                 (size_t)arow * FIN_D + kidx * 32 + quad * 8);
        } else {
            const float* ap = (const float*)Araw +
                 (size_t)arow * FIN_D + kidx * 32 + quad * 8;
            float4 v0 = *(const float4*)ap;
            float4 v1 = *(const float4*)(ap + 4);
            u32 p0 = (u32)f2bf(v0.x) | ((u32)f2bf(v0.y) << 16);
            u32 p1 = (u32)f2bf(v0.z) | ((u32)f2bf(v0.w) << 16);
            u32 p2 = (u32)f2bf(v1.x) | ((u32)f2bf(v1.y) << 16);
            u32 p3 = (u32)f2bf(v1.z) | ((u32)f2bf(v1.w) << 16);
            union { u32 u[4]; bf16x8 v; } cv;
            cv.u[0] = p0; cv.u[1] = p1; cv.u[2] = p2; cv.u[3] = p3;
            a = cv.v;
        }
        const u16* bb = Bp + ((size_t)(kidx * 8) * 64 + lane) * 8;
        #pragma unroll
        for (int ct = 0; ct < 8; ++ct) {
            bf16x8 b = *(const bf16x8*)(bb + (size_t)ct * 512);
            acc[ct] = __builtin_amdgcn_mfma_f32_16x16x32_bf16(a, b, acc[ct], 0, 0, 0);
        }
    }

    #pragma unroll
    for (int reg = 0; reg < 4; ++reg) {
        int grow = m0 + w * 16 + quad * 4 + reg;
        if (grow >= N_NODES) continue;
        #pragma unroll
        for (int ct = 0; ct < 8; ++ct) {
            int col = ct * 16 + cl;
            float v = acc[ct][reg] + loadF(bias, col, f32);
            OutBF[(size_t)grow * HDIM + col] = f2bf(v);
        }
    }
}

// ---------------- Softmax aggregation -> bf16 A-matrix -----------------
template<bool OWN_MAP>
__global__ __launch_bounds__(256) void agg_msg_kernel(
    const int* __restrict__ rp, const int* __restrict__ eidx,
    const u16* __restrict__ HBin, const int* __restrict__ own_map,
    u16* __restrict__ Amsg)
{
    int wave = threadIdx.x >> 6;
    int lane = threadIdx.x & 63;
    int n = blockIdx.x * 4 + wave;
    if (n >= N_NODES) return;
    const u32* HB32 = (const u32*)HBin;
    int nn = OWN_MAP ? own_map[n] : n;
    u32 own = HB32[(size_t)nn * 64 + lane];
    int beg = rp[n], end = rp[n + 1];
    float den0 = 0.f, den1 = 0.f, num0 = 0.f, num1 = 0.f;
    for (int j0 = beg; j0 < end; j0 += 8) {
        int cnt = end - j0; if (cnt > 8) cnt = 8;
        int ss[8];
        #pragma unroll
        for (int t = 0; t < 8; ++t) {
            int j = j0 + t;
            ss[t] = eidx[j < end ? j : end - 1];
        }
        u32 hh[8];
        #pragma unroll
        for (int t = 0; t < 8; ++t)
            hh[t] = HB32[(size_t)ss[t] * 64 + lane];
        #pragma unroll
        for (int t = 0; t < 8; ++t) {
            float valid = (t < cnt) ? 1.f : 0.f;
            float m0 = fmaxf(bf2f((u16)(hh[t] & 0xffff)), 0.f) + 1e-7f;
            float m1 = fmaxf(bf2f((u16)(hh[t] >> 16)),    0.f) + 1e-7f;
            float e0 = __expf(m0) * valid, e1 = __expf(m1) * valid;
            den0 += e0; num0 += m0 * e0;
            den1 += e1; num1 += m1 * e1;
        }
    }
    float a0 = num0 / (den0 + 1e-16f) + bf2f((u16)(own & 0xffff));
    float a1 = num1 / (den1 + 1e-16f) + bf2f((u16)(own >> 16));
    ((u32*)Amsg)[(size_t)n * 64 + lane] = (u32)f2bf(a0) | ((u32)f2bf(a1) << 16);
}

// ---------------- Conv GEMM: h = Amsg @ Wl + bias (+fp16 res) ----------
template<bool RES, bool OWN_MAP, bool WRITE_LN>
__global__ __launch_bounds__(256) void conv_gemm_kernel(
    const u16* __restrict__ Amsg, const int* __restrict__ own_map,
    const u16* __restrict__ Bp, int Bpbase,
    const void* __restrict__ bias, int biasoff,
    const __half* __restrict__ Resid,
    const void* __restrict__ lng, const void* __restrict__ lnb, int lnoff,
    const int* __restrict__ dt,
    __half* __restrict__ OutH, u16* __restrict__ HBout)
{
    const bool f32 = (*dt != 0);
    __shared__ u16 Bsh[16384];
    const int tid  = threadIdx.x;
    const int w    = tid >> 6;
    const int lane = tid & 63;
    const int quad = lane >> 4;
    const int cl   = lane & 15;
    const int m0   = blockIdx.x * 64;

    {
        const uint4* bsrc = (const uint4*)(Bp + Bpbase);
        uint4* bdst = (uint4*)Bsh;
        #pragma unroll
        for (int j = 0; j < 8; ++j)
            bdst[j * 256 + tid] = bsrc[j * 256 + tid];
    }

    int arow = m0 + w * 16 + cl;
    if (arow >= N_NODES) arow = N_NODES - 1;
    bf16x8 afr[4];
    #pragma unroll
    for (int kidx = 0; kidx < 4; ++kidx)
        afr[kidx] = *(const bf16x8*)(Amsg + (size_t)arow * HDIM + kidx * 32 + quad * 8);

    __syncthreads();

    f32x4 acc[8];
    #pragma unroll
    for (int ct = 0; ct < 8; ++ct) acc[ct] = (f32x4){0.f, 0.f, 0.f, 0.f};
    #pragma unroll
    for (int kidx = 0; kidx < 4; ++kidx) {
        const u16* bb = Bsh + ((size_t)(kidx * 8) * 64 + lane) * 8;
        #pragma unroll
        for (int ct = 0; ct < 8; ++ct) {
            bf16x8 b = *(const bf16x8*)(bb + (size_t)ct * 512);
            acc[ct] = __builtin_amdgcn_mfma_f32_16x16x32_bf16(afr[kidx], b, acc[ct], 0, 0, 0);
        }
    }

    #pragma unroll
    for (int reg = 0; reg < 4; ++reg) {
        int n = m0 + w * 16 + quad * 4 + reg;
        if (n >= N_NODES) continue;
        size_t rrow = 0;
        if (RES) rrow = (size_t)(OWN_MAP ? own_map[n] : n) * HDIM;
        float v[8];
        float s1 = 0.f, s2 = 0.f;
        #pragma unroll
        for (int ct = 0; ct < 8; ++ct) {
            int col = ct * 16 + cl;
            float x = acc[ct][reg] + loadF(bias, biasoff + col, f32);
            if (RES) x += __half2float(Resid[rrow + col]);
            v[ct] = x;
            OutH[(size_t)n * HDIM + col] = __float2half(x);
            s1 += x; s2 += x * x;
        }
        if (WRITE_LN) {
            #pragma unroll
            for (int o = 1; o < 16; o <<= 1) {
                s1 += __shfl_xor(s1, o, 64);
                s2 += __shfl_xor(s2, o, 64);
            }
            float mu = s1 * (1.0f / 128.0f);
            float var = s2 * (1.0f / 128.0f) - mu * mu;
            float rs = rsqrtf(fmaxf(var, 0.f) + 1e-5f);
            #pragma unroll
            for (int ct = 0; ct < 8; ++ct) {
                int col = ct * 16 + cl;
                float y = fmaxf((v[ct] - mu) * rs * loadF(lng, lnoff + col, f32)
                                + loadF(lnb, lnoff + col, f32), 0.f);
                HBout[(size_t)n * HDIM + col] = f2bf(y);
            }
        }
    }
}

// ---------------- Final: gather -> LN -> ReLU -> pred -> log_softmax ---
__global__ __launch_bounds__(64) void final_head_kernel(
    const __half* __restrict__ Hsrc, const int* __restrict__ map1,
    const int* __restrict__ fmap,
    const void* __restrict__ g, const void* __restrict__ b, int goff,
    const void* __restrict__ pw, const void* __restrict__ pb,
    const int* __restrict__ dt, void* __restrict__ out)
{
    const bool f32 = (*dt != 0);
    __shared__ float sh[HDIM];
    int i = blockIdx.x;
    int lane = threadIdx.x;
    int jj = map1[fmap[i]];
    __half2 hv = *((const __half2*)(Hsrc + (size_t)jj * HDIM) + lane);
    float2 v = __half22float2(hv);
    float mu = wave_sum(v.x + v.y) * (1.0f / 128.0f);
    float d0 = v.x - mu, d1 = v.y - mu;
    float var = wave_sum(d0 * d0 + d1 * d1) * (1.0f / 128.0f);
    float rs = rsqrtf(var + 1e-5f);
    int f0 = lane * 2;
    sh[f0]     = fmaxf(d0 * rs * loadF(g, goff + f0, f32)     + loadF(b, goff + f0, f32),     0.0f);
    sh[f0 + 1] = fmaxf(d1 * rs * loadF(g, goff + f0 + 1, f32) + loadF(b, goff + f0 + 1, f32), 0.0f);
    __syncthreads();
    float acc = -1e30f;
    if (lane < NCLS) {
        acc = loadF(pb, lane, f32);
        #pragma unroll 4
        for (int k = 0; k < HDIM; ++k)
            acc = fmaf(sh[k], loadF(pw, k * NCLS + lane, f32), acc);
    }
    float mx = wave_max(acc);
    float ex = (lane < NCLS) ? __expf(acc - mx) : 0.0f;
    float sum = wave_sum(ex);
    if (lane < NCLS) {
        float r = acc - mx - logf(sum);
        if (f32) ((float*)out)[(size_t)i * NCLS + lane] = r;
        else     ((u16*)out)[(size_t)i * NCLS + lane] = f2bf(r);
    }
}

extern "C" void kernel_launch(void* const* d_in, const int* in_sizes, int n_in,
                              void* d_out, int out_size, void* d_ws, size_t ws_size,
                              hipStream_t stream) {
    const void* x       = d_in[0];
    const int* src      = (const int*)d_in[1];
    const int* dst      = (const int*)d_in[2];
    const int* node_map = (const int*)d_in[3];
    const int* fmap     = (const int*)d_in[4];
    const void* enc_w   = d_in[5];
    const void* enc_b   = d_in[6];
    const void* gcn_w   = d_in[7];
    const void* gcn_b   = d_in[8];
    const void* ln_g    = d_in[9];
    const void* ln_b    = d_in[10];
    const void* pred_w  = d_in[11];
    const void* pred_b  = d_in[12];

    char* ws = (char*)d_ws;
    const size_t szH = (size_t)N_NODES * HDIM * sizeof(u16);     // 25.6 MB
    __half* Pa  = (__half*)ws;  ws += szH;   // h1, then h3 (fp16)
    __half* Pb  = (__half*)ws;  ws += szH;   // h2 (fp16)
    u16*   HBa  = (u16*)ws;     ws += szH;   // msg0, then msg2 (bf16)
    u16*   HBb  = (u16*)ws;     ws += szH;   // msg1 (bf16)
    u16*   Amsg = (u16*)ws;     ws += szH;   // per-layer GEMM A matrix (bf16)
    int*   FLAG = (int*)ws;     ws += 1024;
    u16*   Bp   = (u16*)ws;     ws += (size_t)(32768 + 3 * 16384) * 2 + 1024;
    int*  deg2  = (int*)ws;  ws += (size_t)2 * NP2 * 4;
    int*  rp0   = (int*)ws;  ws += (size_t)(N_NODES + 2) * 4;
    int*  rp1   = (int*)ws;  ws += (size_t)(N_NODES + 2) * 4;
    int*  ei0   = (int*)ws;  ws += (size_t)N_EDGES * 4;
    int*  ei1   = (int*)ws;  ws += (size_t)N_EDGES * 4;
    int2* tmp   = (int2*)ws; ws += (size_t)2 * N_EDGES * 8;
    int*  csum  = (int*)ws;  ws += 2048;
    int*  coff  = (int*)ws;  ws += 2048;
    int*  bcur  = (int*)ws;  ws += (size_t)2 * NCHUNK * 16 * 4 + 1024;  // padded

    dim3 blk(256);
    const int ggrid = (N_NODES + 63) / 64;       // 1563
    const int egrid = (N_EDGES + 255) / 256;
    const int agrid = (N_NODES + 3) / 4;
    const int pgrid = (32768 + 3 * 16384 + 255) / 256;

    dtype_detect_kernel<<<1, blk, 0, stream>>>((const u16*)x, FLAG);
    pack_b_kernel<<<pgrid, blk, 0, stream>>>(enc_w, gcn_w, FLAG, Bp);

    // ---- CSR build: hist -> scan -> block-radix partition -> bucket sort ----
    hipMemsetAsync(deg2, 0, (size_t)2 * NP2 * 4, stream);
    hist2_kernel<<<2 * egrid, blk, 0, stream>>>(dst, deg2, egrid);
    csum2_kernel<<<2 * NCHUNK, blk, 0, stream>>>(deg2, csum);
    coff2_kernel<<<1, blk, 0, stream>>>(csum, coff, bcur);
    scan2_kernel<<<2 * NCHUNK, blk, 0, stream>>>(deg2, coff, rp0, rp1);
    bucket_part_kernel<<<2 * PNB, blk, 0, stream>>>(src, dst, node_map, bcur, tmp);
    bucket_sort_kernel<<<2 * NCHUNK, blk, 0, stream>>>(tmp, rp0, rp1, coff, csum,
                                                       ei0, ei1);

    // encoder: HBa = bf16(x @ enc_w + enc_b)   (= msg matrix for conv0)
    enc_gemm_kernel<<<ggrid, blk, 0, stream>>>(x, Bp, enc_b, FLAG, HBa);

    // layer 0: Amsg = agg0(HBa)+HBa ; Pa = Amsg@w0+b0 ; HBb = relu(LN(Pa,ln0))
    agg_msg_kernel<false><<<agrid, blk, 0, stream>>>(rp0, ei0, HBa, nullptr, Amsg);
    conv_gemm_kernel<false, false, true><<<ggrid, blk, 0, stream>>>(
        Amsg, nullptr, Bp, 32768, gcn_b, 0, nullptr,
        ln_g, ln_b, 0, FLAG, Pa, HBb);

    // layer 1: Amsg = agg0(HBb)+HBb ; Pb = Amsg@w1+b1+Pa ; HBa = relu(LN(Pb,ln1))
    agg_msg_kernel<false><<<agrid, blk, 0, stream>>>(rp0, ei0, HBb, nullptr, Amsg);
    conv_gemm_kernel<true, false, true><<<ggrid, blk, 0, stream>>>(
        Amsg, nullptr, Bp, 32768 + 16384, gcn_b, 128, Pa,
        ln_g, ln_b, 128, FLAG, Pb, HBa);

    // layer 2 (permute via node_map[0], index-composed into CSR1):
    // Amsg = agg1(HBa)+HBa[map0] ; Pa = Amsg@w2+b2+Pb[map0]
    agg_msg_kernel<true><<<agrid, blk, 0, stream>>>(rp1, ei1, HBa, node_map, Amsg);
    conv_gemm_kernel<true, true, false><<<ggrid, blk, 0, stream>>>(
        Amsg, node_map, Bp, 32768 + 2 * 16384, gcn_b, 256, Pb,
        ln_g, ln_b, 256, FLAG, Pa, nullptr);

    // final head: Pa[node_map[1][final_map[i]]] -> LN(ln2) -> pred -> log_softmax
    final_head_kernel<<<NOUT_D, dim3(64), 0, stream>>>(
        Pa, node_map + N_NODES, fmap, ln_g, ln_b, 256, pred_w, pred_b, FLAG,
        (void*)d_out);
}